// Round 1
// baseline (645.598 us; speedup 1.0000x reference)
//
#include <hip/hip_runtime.h>
#include <hip/hip_fp16.h>

// Problem constants
#define DB   768      // model dim = dim_k = dim_v
#define SEQ  2048
#define BATCH 8
#define NTOK (BATCH*SEQ)   // 16384

// softmax scale applied AFTER softmax (non-standard, per reference)
#define NORM_F 0.036084391824351613f

typedef __attribute__((ext_vector_type(8))) short  short8;   // 8 bf16 = 16B (MFMA frag)
typedef __attribute__((ext_vector_type(4))) short  short4v;  // 8B
typedef __attribute__((ext_vector_type(4))) float  f32x4;    // MFMA acc
typedef __attribute__((ext_vector_type(4))) float  float4v;  // 16B fp32 load

// ---- bf16 / fp16 bit helpers -------------------------------------------------
__device__ __forceinline__ unsigned short f2bf(float f) {
  unsigned int u = __float_as_uint(f);
  u += 0x7fffu + ((u >> 16) & 1u);      // round-to-nearest-even
  return (unsigned short)(u >> 16);
}
__device__ __forceinline__ float bf2f(unsigned short h) {
  return __uint_as_float(((unsigned int)h) << 16);
}
__device__ __forceinline__ float h2f_bits(unsigned short h) {
  __half v; __builtin_memcpy(&v, &h, 2); return __half2float(v);
}
__device__ __forceinline__ unsigned short f2h_bits(float f) {
  __half v = __float2half(f); unsigned short u; __builtin_memcpy(&u, &v, 2); return u;
}

// =============================================================================
// Kernel 0: transpose W [768(d),768(n)] -> WT [z][n][d], split fp32 -> bf16 hi/lo
// =============================================================================
__global__ __launch_bounds__(256) void wsplit_kernel(
    const float* __restrict__ Wq, const float* __restrict__ Wk,
    const float* __restrict__ Wv,
    unsigned short* __restrict__ WTh, unsigned short* __restrict__ WTl) {
  int z = blockIdx.z;
  const float* W = (z == 0) ? Wq : ((z == 1) ? Wk : Wv);
  int idx = blockIdx.x * 256 + threadIdx.x;      // idx = n*768 + d
  int n = idx / DB, d = idx % DB;
  float v = W[(size_t)d * DB + n];
  unsigned short h = f2bf(v);
  WTh[(size_t)z * DB * DB + idx] = h;
  WTl[(size_t)z * DB * DB + idx] = f2bf(v - bf2f(h));
}

// =============================================================================
// Kernel 1: QKV projection.  C[m,n] = sum_d X[m,d] * W[d,n] + bias[n]
// 128x128 tile, BK=32, 4 waves in 2x2, each wave 4x4 of 16x16x32 MFMA.
// Split-bf16: acc += Xh*Wh + Xh*Wl + Xl*Wh  (~fp32 accuracy).
// z=0 -> Qh/Ql, z=1 -> Kh/Kl, z=2 -> VT[b][n][s] (bf16 hi only).
// =============================================================================
__global__ __launch_bounds__(256) void proj_kernel(
    const float* __restrict__ X,
    const unsigned short* __restrict__ WTh, const unsigned short* __restrict__ WTl,
    const float* __restrict__ bq, const float* __restrict__ bk,
    const float* __restrict__ bv,
    unsigned short* __restrict__ Qh, unsigned short* __restrict__ Ql,
    unsigned short* __restrict__ Kh, unsigned short* __restrict__ Kl,
    unsigned short* __restrict__ VT) {
  __shared__ unsigned short Ah[128 * 40], Al[128 * 40];  // pad 32->40: conflict-free frags
  __shared__ unsigned short Bh[128 * 40], Bl[128 * 40];

  int z  = blockIdx.z;
  int n0 = blockIdx.x << 7;
  int m0 = blockIdx.y << 7;
  int tid = threadIdx.x;
  int wave = tid >> 6, lane = tid & 63;
  int wm = wave & 1, wn = wave >> 1;
  int quad = lane >> 4, l16 = lane & 15;

  const unsigned short* WThz = WTh + (size_t)z * DB * DB;
  const unsigned short* WTlz = WTl + (size_t)z * DB * DB;

  f32x4 acc[4][4];
#pragma unroll
  for (int mi = 0; mi < 4; mi++)
#pragma unroll
    for (int ni = 0; ni < 4; ni++) acc[mi][ni] = (f32x4){0.f, 0.f, 0.f, 0.f};

  for (int kt = 0; kt < DB; kt += 32) {
    // ---- stage A: X fp32 tile [128x32] -> bf16 hi/lo in LDS
    const float* ga = X + (size_t)m0 * DB + kt;
#pragma unroll
    for (int r = 0; r < 4; r++) {
      int idx = (r << 10) + (tid << 2);
      int row = idx >> 5, col = idx & 31;
      float4v v = *(const float4v*)(ga + (size_t)row * DB + col);
      short4v hv, lv;
#pragma unroll
      for (int j = 0; j < 4; j++) {
        unsigned short h = f2bf(v[j]);
        hv[j] = (short)h;
        lv[j] = (short)f2bf(v[j] - bf2f(h));
      }
      *(short4v*)&Ah[row * 40 + col] = hv;
      *(short4v*)&Al[row * 40 + col] = lv;
    }
    // ---- stage B: WT bf16 tiles [128x32]
    const unsigned short* gbh = WThz + (size_t)n0 * DB + kt;
    const unsigned short* gbl = WTlz + (size_t)n0 * DB + kt;
#pragma unroll
    for (int r = 0; r < 2; r++) {
      int idx = (r << 11) + (tid << 3);
      int row = idx >> 5, col = idx & 31;
      int lo = row * 40 + col;
      *(short8*)&Bh[lo] = *(const short8*)(gbh + (size_t)row * DB + col);
      *(short8*)&Bl[lo] = *(const short8*)(gbl + (size_t)row * DB + col);
    }
    __syncthreads();

    short8 afh[4], afl[4], bfh[4], bfl[4];
#pragma unroll
    for (int mi = 0; mi < 4; mi++) {
      int r = (wm * 64 + mi * 16 + l16) * 40 + quad * 8;
      afh[mi] = *(const short8*)&Ah[r];
      afl[mi] = *(const short8*)&Al[r];
    }
#pragma unroll
    for (int ni = 0; ni < 4; ni++) {
      int r = (wn * 64 + ni * 16 + l16) * 40 + quad * 8;
      bfh[ni] = *(const short8*)&Bh[r];
      bfl[ni] = *(const short8*)&Bl[r];
    }
#pragma unroll
    for (int mi = 0; mi < 4; mi++)
#pragma unroll
      for (int ni = 0; ni < 4; ni++) {
        acc[mi][ni] = __builtin_amdgcn_mfma_f32_16x16x32_bf16(afh[mi], bfh[ni], acc[mi][ni], 0, 0, 0);
        acc[mi][ni] = __builtin_amdgcn_mfma_f32_16x16x32_bf16(afh[mi], bfl[ni], acc[mi][ni], 0, 0, 0);
        acc[mi][ni] = __builtin_amdgcn_mfma_f32_16x16x32_bf16(afl[mi], bfh[ni], acc[mi][ni], 0, 0, 0);
      }
    __syncthreads();
  }

  const float* bias = (z == 0) ? bq : ((z == 1) ? bk : bv);
#pragma unroll
  for (int mi = 0; mi < 4; mi++)
#pragma unroll
    for (int ni = 0; ni < 4; ni++)
#pragma unroll
      for (int r = 0; r < 4; r++) {
        int gm = m0 + wm * 64 + mi * 16 + quad * 4 + r;  // C/D: row=quad*4+reg
        int gn = n0 + wn * 64 + ni * 16 + l16;           //      col=lane&15
        float val = acc[mi][ni][r] + bias[gn];
        unsigned short h = f2bf(val);
        if (z == 0) {
          Qh[(size_t)gm * DB + gn] = h;
          Ql[(size_t)gm * DB + gn] = f2bf(val - bf2f(h));
        } else if (z == 1) {
          Kh[(size_t)gm * DB + gn] = h;
          Kl[(size_t)gm * DB + gn] = f2bf(val - bf2f(h));
        } else {
          int bb = gm >> 11, s = gm & 2047;              // V transposed: VT[b][n][s]
          VT[((size_t)bb * DB + gn) * SEQ + s] = h;
        }
      }
}

// =============================================================================
// Kernel 2: scores[b,q,t] = (Q[b,q,:] . K[b,t,:]) * mask[b,q], stored fp16.
// Split-bf16 3-MFMA for ~fp32 score accuracy.
// =============================================================================
__global__ __launch_bounds__(256) void scores_kernel(
    const unsigned short* __restrict__ Qh, const unsigned short* __restrict__ Ql,
    const unsigned short* __restrict__ Kh, const unsigned short* __restrict__ Kl,
    const int* __restrict__ mask, unsigned short* __restrict__ SC) {
  __shared__ unsigned short Ah[128 * 40], Al[128 * 40];
  __shared__ unsigned short Bh[128 * 40], Bl[128 * 40];

  int b  = blockIdx.z;
  int t0 = blockIdx.x << 7;
  int q0 = blockIdx.y << 7;
  int tid = threadIdx.x;
  int wave = tid >> 6, lane = tid & 63;
  int wm = wave & 1, wn = wave >> 1;
  int quad = lane >> 4, l16 = lane & 15;

  const unsigned short* qh = Qh + ((size_t)b * SEQ + q0) * DB;
  const unsigned short* ql = Ql + ((size_t)b * SEQ + q0) * DB;
  const unsigned short* kh = Kh + ((size_t)b * SEQ + t0) * DB;
  const unsigned short* kl = Kl + ((size_t)b * SEQ + t0) * DB;

  f32x4 acc[4][4];
#pragma unroll
  for (int mi = 0; mi < 4; mi++)
#pragma unroll
    for (int ni = 0; ni < 4; ni++) acc[mi][ni] = (f32x4){0.f, 0.f, 0.f, 0.f};

  for (int kt = 0; kt < DB; kt += 32) {
#pragma unroll
    for (int r = 0; r < 2; r++) {
      int idx = (r << 11) + (tid << 3);
      int row = idx >> 5, col = idx & 31;
      size_t go = (size_t)row * DB + kt + col;
      int lo = row * 40 + col;
      *(short8*)&Ah[lo] = *(const short8*)(qh + go);
      *(short8*)&Al[lo] = *(const short8*)(ql + go);
      *(short8*)&Bh[lo] = *(const short8*)(kh + go);
      *(short8*)&Bl[lo] = *(const short8*)(kl + go);
    }
    __syncthreads();

    short8 afh[4], afl[4], bfh[4], bfl[4];
#pragma unroll
    for (int mi = 0; mi < 4; mi++) {
      int r = (wm * 64 + mi * 16 + l16) * 40 + quad * 8;
      afh[mi] = *(const short8*)&Ah[r];
      afl[mi] = *(const short8*)&Al[r];
    }
#pragma unroll
    for (int ni = 0; ni < 4; ni++) {
      int r = (wn * 64 + ni * 16 + l16) * 40 + quad * 8;
      bfh[ni] = *(const short8*)&Bh[r];
      bfl[ni] = *(const short8*)&Bl[r];
    }
#pragma unroll
    for (int mi = 0; mi < 4; mi++)
#pragma unroll
      for (int ni = 0; ni < 4; ni++) {
        acc[mi][ni] = __builtin_amdgcn_mfma_f32_16x16x32_bf16(afh[mi], bfh[ni], acc[mi][ni], 0, 0, 0);
        acc[mi][ni] = __builtin_amdgcn_mfma_f32_16x16x32_bf16(afh[mi], bfl[ni], acc[mi][ni], 0, 0, 0);
        acc[mi][ni] = __builtin_amdgcn_mfma_f32_16x16x32_bf16(afl[mi], bfh[ni], acc[mi][ni], 0, 0, 0);
      }
    __syncthreads();
  }

#pragma unroll
  for (int mi = 0; mi < 4; mi++)
#pragma unroll
    for (int r = 0; r < 4; r++) {
      int gq = q0 + wm * 64 + mi * 16 + quad * 4 + r;
      float mval = (float)mask[b * SEQ + gq];   // multiplicative row mask
#pragma unroll
      for (int ni = 0; ni < 4; ni++) {
        int gt = t0 + wn * 64 + ni * 16 + l16;
        SC[((size_t)b * SEQ + gq) * SEQ + gt] = f2h_bits(acc[mi][ni][r] * mval);
      }
    }
}

// =============================================================================
// Kernel 3: row softmax over fp16 scores, write bf16 (softmax * NORM) in place.
// One block per row (8 fp16 per thread). Masked rows (all-zero) -> uniform.
// =============================================================================
__global__ __launch_bounds__(256) void softmax_kernel(unsigned short* __restrict__ SC) {
  size_t row = blockIdx.x;
  unsigned short* p = SC + row * SEQ;
  int tid = threadIdx.x;

  short8 hv = *(const short8*)(p + (tid << 3));
  float v[8];
#pragma unroll
  for (int j = 0; j < 8; j++) v[j] = h2f_bits((unsigned short)hv[j]);

  float m = v[0];
#pragma unroll
  for (int j = 1; j < 8; j++) m = fmaxf(m, v[j]);
#pragma unroll
  for (int off = 32; off >= 1; off >>= 1) m = fmaxf(m, __shfl_down(m, off));

  __shared__ float red[8];
  int w = tid >> 6;
  if ((tid & 63) == 0) red[w] = m;
  __syncthreads();
  m = fmaxf(fmaxf(red[0], red[1]), fmaxf(red[2], red[3]));

  float e[8], s = 0.f;
#pragma unroll
  for (int j = 0; j < 8; j++) { e[j] = __expf(v[j] - m); s += e[j]; }
#pragma unroll
  for (int off = 32; off >= 1; off >>= 1) s += __shfl_down(s, off);
  if ((tid & 63) == 0) red[4 + w] = s;
  __syncthreads();
  float L = red[4] + red[5] + red[6] + red[7];

  float scale = NORM_F / L;   // fold post-softmax 1/sqrt(dim_k) into weights
  short8 ov;
#pragma unroll
  for (int j = 0; j < 8; j++) ov[j] = (short)f2bf(e[j] * scale);
  *(short8*)(p + (tid << 3)) = ov;   // same bytes this thread read: no hazard
}

// =============================================================================
// Kernel 4: out[b,q,v] = sum_t attn[b,q,t] * V[b,t,v]   (attn bf16, VT bf16)
// =============================================================================
__global__ __launch_bounds__(256) void pv_kernel(
    const unsigned short* __restrict__ AT, const unsigned short* __restrict__ VT,
    float* __restrict__ out) {
  __shared__ unsigned short Ah[128 * 40], Bh[128 * 40];

  int b  = blockIdx.z;
  int v0 = blockIdx.x << 7;
  int q0 = blockIdx.y << 7;
  int tid = threadIdx.x;
  int wave = tid >> 6, lane = tid & 63;
  int wm = wave & 1, wn = wave >> 1;
  int quad = lane >> 4, l16 = lane & 15;

  const unsigned short* at = AT + ((size_t)b * SEQ + q0) * SEQ;
  const unsigned short* vt = VT + ((size_t)b * DB + v0) * SEQ;

  f32x4 acc[4][4];
#pragma unroll
  for (int mi = 0; mi < 4; mi++)
#pragma unroll
    for (int ni = 0; ni < 4; ni++) acc[mi][ni] = (f32x4){0.f, 0.f, 0.f, 0.f};

  for (int kt = 0; kt < SEQ; kt += 32) {
#pragma unroll
    for (int r = 0; r < 2; r++) {
      int idx = (r << 11) + (tid << 3);
      int row = idx >> 5, col = idx & 31;
      int lo = row * 40 + col;
      *(short8*)&Ah[lo] = *(const short8*)(at + (size_t)row * SEQ + kt + col);
      *(short8*)&Bh[lo] = *(const short8*)(vt + (size_t)row * SEQ + kt + col);
    }
    __syncthreads();

    short8 af[4], bf[4];
#pragma unroll
    for (int mi = 0; mi < 4; mi++)
      af[mi] = *(const short8*)&Ah[(wm * 64 + mi * 16 + l16) * 40 + quad * 8];
#pragma unroll
    for (int ni = 0; ni < 4; ni++)
      bf[ni] = *(const short8*)&Bh[(wn * 64 + ni * 16 + l16) * 40 + quad * 8];
#pragma unroll
    for (int mi = 0; mi < 4; mi++)
#pragma unroll
      for (int ni = 0; ni < 4; ni++)
        acc[mi][ni] = __builtin_amdgcn_mfma_f32_16x16x32_bf16(af[mi], bf[ni], acc[mi][ni], 0, 0, 0);
    __syncthreads();
  }

#pragma unroll
  for (int mi = 0; mi < 4; mi++)
#pragma unroll
    for (int ni = 0; ni < 4; ni++)
#pragma unroll
      for (int r = 0; r < 4; r++) {
        int gq = q0 + wm * 64 + mi * 16 + quad * 4 + r;
        int gv = v0 + wn * 64 + ni * 16 + l16;
        out[((size_t)b * SEQ + gq) * DB + gv] = acc[mi][ni][r];
      }
}

// =============================================================================
extern "C" void kernel_launch(void* const* d_in, const int* in_sizes, int n_in,
                              void* d_out, int out_size, void* d_ws, size_t ws_size,
                              hipStream_t stream) {
  const float* x    = (const float*)d_in[0];
  const int*   mask = (const int*)d_in[1];
  const float* Wq   = (const float*)d_in[2];
  const float* bq   = (const float*)d_in[3];
  const float* Wk   = (const float*)d_in[4];
  const float* bk   = (const float*)d_in[5];
  const float* Wv   = (const float*)d_in[6];
  const float* bv   = (const float*)d_in[7];
  float* out = (float*)d_out;
  char* ws = (char*)d_ws;

  // workspace layout (~191 MB total)
  const size_t SZ = (size_t)NTOK * DB * 2;                 // 25,165,824 per tensor
  unsigned short* Qh = (unsigned short*)(ws + 0 * SZ);
  unsigned short* Ql = (unsigned short*)(ws + 1 * SZ);
  unsigned short* Kh = (unsigned short*)(ws + 2 * SZ);
  unsigned short* Kl = (unsigned short*)(ws + 3 * SZ);
  unsigned short* VT = (unsigned short*)(ws + 4 * SZ);
  unsigned short* SC = (unsigned short*)(ws + 5 * SZ);     // fp16 scores -> bf16 attn, 67 MB
  unsigned short* WTh = (unsigned short*)(ws + 5 * SZ + (size_t)BATCH * SEQ * SEQ * 2);
  unsigned short* WTl = WTh + (size_t)3 * DB * DB;

  wsplit_kernel<<<dim3(DB * DB / 256, 1, 3), 256, 0, stream>>>(Wq, Wk, Wv, WTh, WTl);
  proj_kernel<<<dim3(DB / 128, NTOK / 128, 3), 256, 0, stream>>>(
      x, WTh, WTl, bq, bk, bv, Qh, Ql, Kh, Kl, VT);
  scores_kernel<<<dim3(SEQ / 128, SEQ / 128, BATCH), 256, 0, stream>>>(
      Qh, Ql, Kh, Kl, mask, SC);
  softmax_kernel<<<dim3(NTOK), 256, 0, stream>>>(SC);
  pv_kernel<<<dim3(DB / 128, SEQ / 128, BATCH), 256, 0, stream>>>(SC, VT, out);
}